// Round 2
// baseline (2812.544 us; speedup 1.0000x reference)
//
#include <hip/hip_runtime.h>
#include <hip/hip_bf16.h>

#define NUM_USERS 100000
#define NUM_ITEMS 50000
#define EMBED     64
#define S_NNZ     (NUM_USERS * 32)
#define R_NNZ     (NUM_USERS * 50)
#define BATCH     8192

// ---------------- kernels ----------------

// COO SpMM scatter: Y[row] += val * X[col]. One edge per 64-lane wave, lane = dim.
__global__ void k_spmm(const int* __restrict__ rows, const int* __restrict__ cols,
                       const float* __restrict__ vals,
                       const float* __restrict__ X, float* __restrict__ Y, int nnz) {
    int e    = blockIdx.x * (blockDim.x >> 6) + (threadIdx.x >> 6);
    int lane = threadIdx.x & 63;
    if (e >= nnz) return;
    int   r = rows[e];
    int   c = cols[e];
    float v = vals[e];
    atomicAdd(&Y[(size_t)r * EMBED + lane], v * X[(size_t)c * EMBED + lane]);
}

// Uout <- relu(concat([Agg, Uin]) @ W + b). 4 rows per 256-thread block.
// Safe when Uin == Uout: each block stages its 4 rows into LDS before writing.
__global__ __launch_bounds__(256) void k_layer(const float* __restrict__ Agg,
                                               const float* __restrict__ Uin,
                                               float* __restrict__ Uout,
                                               const float* __restrict__ W,
                                               const float* __restrict__ b) {
    __shared__ float Wl[128 * 64];   // 32 KB
    __shared__ float xs[4][128];
    int t = threadIdx.x;
    for (int i = t; i < 128 * 64; i += 256) Wl[i] = W[i];
    int rl = t >> 6;       // local row 0..3 (one wave per row)
    int c  = t & 63;       // output column
    int r  = blockIdx.x * 4 + rl;
    if (r < NUM_USERS) {
        xs[rl][c]      = Agg[(size_t)r * EMBED + c];
        xs[rl][64 + c] = Uin[(size_t)r * EMBED + c];
    }
    __syncthreads();
    if (r >= NUM_USERS) return;
    float acc = b[c];
#pragma unroll
    for (int k = 0; k < 128; ++k) acc = fmaf(xs[rl][k], Wl[k * 64 + c], acc);
    Uout[(size_t)r * EMBED + c] = fmaxf(acc, 0.0f);
}

// Final gathers: bu from fp32 user_g, bp/bn from V.
__global__ void k_gather(const float* __restrict__ Ug, const float* __restrict__ V,
                         const int* __restrict__ bu, const int* __restrict__ bp,
                         const int* __restrict__ bn, float* __restrict__ out) {
    int i = blockIdx.x * blockDim.x + threadIdx.x;
    if (i >= BATCH * EMBED) return;
    int row = i >> 6, l = i & 63;
    out[i]                     = Ug[(size_t)bu[row] * EMBED + l];
    out[BATCH * EMBED + i]     = V[(size_t)bp[row] * EMBED + l];
    out[2 * BATCH * EMBED + i] = V[(size_t)bn[row] * EMBED + l];
}

// ---------------- launch ----------------

extern "C" void kernel_launch(void* const* d_in, const int* in_sizes, int n_in,
                              void* d_out, int out_size, void* d_ws, size_t ws_size,
                              hipStream_t stream) {
    const int*   batch_user = (const int*)d_in[0];
    const int*   batch_pos  = (const int*)d_in[1];
    const int*   batch_neg  = (const int*)d_in[2];
    const float* U     = (const float*)d_in[3];
    const float* V     = (const float*)d_in[4];
    const float* W0    = (const float*)d_in[5];
    const float* b0    = (const float*)d_in[6];
    const float* W1    = (const float*)d_in[7];
    const float* b1    = (const float*)d_in[8];
    const int*   S_row = (const int*)d_in[9];
    const int*   S_col = (const int*)d_in[10];
    const float* S_val = (const float*)d_in[11];
    const int*   R_row = (const int*)d_in[12];
    const int*   R_col = (const int*)d_in[13];
    const float* R_val = (const float*)d_in[14];
    float* out = (float*)d_out;

    const size_t tabElems = (size_t)NUM_USERS * EMBED;        // 6.4M floats
    float* A = (float*)d_ws;                                  // current U (fp32), 25.6 MB
    float* B = A + tabElems;                                  // agg scratch,      25.6 MB

    const int spmmS_blocks = (S_NNZ + 3) / 4;   // 4 edges (waves) per 256-thread block
    const int spmmR_blocks = (R_NNZ + 3) / 4;
    const int layer_blocks = (NUM_USERS + 3) / 4;

    // layer 0: B = S @ U_in ; A = relu([B||U_in] @ W0 + b0)
    hipMemsetAsync(B, 0, tabElems * sizeof(float), stream);
    k_spmm<<<spmmS_blocks, 256, 0, stream>>>(S_row, S_col, S_val, U, B, S_NNZ);
    k_layer<<<layer_blocks, 256, 0, stream>>>(B, U, A, W0, b0);

    // layer 1: B = S @ A ; A = relu([B||A] @ W1 + b1)   (in-place on A)
    hipMemsetAsync(B, 0, tabElems * sizeof(float), stream);
    k_spmm<<<spmmS_blocks, 256, 0, stream>>>(S_row, S_col, S_val, A, B, S_NNZ);
    k_layer<<<layer_blocks, 256, 0, stream>>>(B, A, A, W1, b1);

    // user_g: A += R @ V
    k_spmm<<<spmmR_blocks, 256, 0, stream>>>(R_row, R_col, R_val, V, A, R_NNZ);

    // gathers
    k_gather<<<(BATCH * EMBED + 255) / 256, 256, 0, stream>>>(A, V, batch_user, batch_pos, batch_neg, out);
}

// Round 3
// 2196.956 us; speedup vs baseline: 1.2802x; 1.2802x over previous
//
#include <hip/hip_runtime.h>
#include <hip/hip_bf16.h>

#define NUM_USERS 100000
#define NUM_ITEMS 50000
#define EMBED     64
#define S_NNZ     (NUM_USERS * 32)
#define R_NNZ     (NUM_USERS * 50)
#define BATCH     8192

// ---------------- CSR build ----------------

__global__ void k_hist(const int* __restrict__ rows, int* __restrict__ cnt, int nnz) {
    int e = blockIdx.x * blockDim.x + threadIdx.x;
    if (e < nnz) atomicAdd(&cnt[rows[e]], 1);
}

// pass 1: per-block (1024-wide) scan; write per-element exclusive-within-block, and block total
__global__ __launch_bounds__(1024) void k_scan1(const int* __restrict__ cnt, int* __restrict__ excl,
                                                int* __restrict__ bsums, int n) {
    __shared__ int buf[1024];
    int t = threadIdx.x;
    int i = blockIdx.x * 1024 + t;
    int x = (i < n) ? cnt[i] : 0;
    buf[t] = x;
    __syncthreads();
    for (int off = 1; off < 1024; off <<= 1) {
        int y = (t >= off) ? buf[t - off] : 0;
        __syncthreads();
        buf[t] += y;
        __syncthreads();
    }
    if (i < n) excl[i] = buf[t] - x;
    if (t == 1023) bsums[blockIdx.x] = buf[1023];
}

// pass 2: single block scans the block sums (nb <= 1024); also writes rowptr[n] = total
__global__ __launch_bounds__(1024) void k_scan2(int* __restrict__ bsums, int nb, int* __restrict__ total_slot) {
    __shared__ int buf[1024];
    int t = threadIdx.x;
    int x = (t < nb) ? bsums[t] : 0;
    buf[t] = x;
    __syncthreads();
    for (int off = 1; off < 1024; off <<= 1) {
        int y = (t >= off) ? buf[t - off] : 0;
        __syncthreads();
        buf[t] += y;
        __syncthreads();
    }
    if (t < nb) bsums[t] = buf[t] - x;
    if (t == 1023) total_slot[0] = buf[1023];
}

// pass 3: add block offsets; duplicate result into wofs (scatter cursor)
__global__ void k_scan3(int* __restrict__ rowptr, int* __restrict__ wofs, const int* __restrict__ bsums, int n) {
    int i = blockIdx.x * blockDim.x + threadIdx.x;
    if (i < n) {
        int v = rowptr[i] + bsums[i >> 10];
        rowptr[i] = v;
        wofs[i]   = v;
    }
}

// counting-sort scatter: place each edge at its row's cursor
__global__ void k_scatter(const int* __restrict__ rows, const int* __restrict__ cols,
                          const float* __restrict__ vals, int* __restrict__ wofs,
                          int* __restrict__ colE, float* __restrict__ valE, int nnz) {
    int e = blockIdx.x * blockDim.x + threadIdx.x;
    if (e >= nnz) return;
    int r   = rows[e];
    int pos = atomicAdd(&wofs[r], 1);
    colE[pos] = cols[e];
    valE[pos] = vals[e];
}

// ---------------- SpMM (CSR, gather, no atomics) ----------------
// One 64-lane wave per row; lane = embed dim; acc in register; one coalesced write.
__global__ __launch_bounds__(256) void k_spmm_csr(const int* __restrict__ rowptr,
                                                  const int* __restrict__ colE,
                                                  const float* __restrict__ valE,
                                                  const float* __restrict__ X,
                                                  float* __restrict__ Y,
                                                  int n_rows, int accumulate) {
    int w    = blockIdx.x * (blockDim.x >> 6) + (threadIdx.x >> 6);
    int lane = threadIdx.x & 63;
    if (w >= n_rows) return;
    int beg = rowptr[w], end = rowptr[w + 1];
    float acc = accumulate ? Y[(size_t)w * EMBED + lane] : 0.0f;
    for (int j = beg; j < end; ++j) {
        int   c = colE[j];          // wave-uniform -> broadcast load
        float v = valE[j];
        acc = fmaf(v, X[(size_t)c * EMBED + lane], acc);
    }
    Y[(size_t)w * EMBED + lane] = acc;
}

// ---------------- dense layer ----------------
// Uout <- relu(concat([Agg, Uin]) @ W + b). 4 rows per 256-thread block.
__global__ __launch_bounds__(256) void k_layer(const float* __restrict__ Agg,
                                               const float* __restrict__ Uin,
                                               float* __restrict__ Uout,
                                               const float* __restrict__ W,
                                               const float* __restrict__ b) {
    __shared__ float Wl[128 * 64];   // 32 KB
    __shared__ float xs[4][128];
    int t = threadIdx.x;
    for (int i = t; i < 128 * 64; i += 256) Wl[i] = W[i];
    int rl = t >> 6;
    int c  = t & 63;
    int r  = blockIdx.x * 4 + rl;
    if (r < NUM_USERS) {
        xs[rl][c]      = Agg[(size_t)r * EMBED + c];
        xs[rl][64 + c] = Uin[(size_t)r * EMBED + c];
    }
    __syncthreads();
    if (r >= NUM_USERS) return;
    float acc = b[c];
#pragma unroll
    for (int k = 0; k < 128; ++k) acc = fmaf(xs[rl][k], Wl[k * 64 + c], acc);
    Uout[(size_t)r * EMBED + c] = fmaxf(acc, 0.0f);
}

// ---------------- final gathers ----------------
__global__ void k_gather(const float* __restrict__ Ug, const float* __restrict__ V,
                         const int* __restrict__ bu, const int* __restrict__ bp,
                         const int* __restrict__ bn, float* __restrict__ out) {
    int i = blockIdx.x * blockDim.x + threadIdx.x;
    if (i >= BATCH * EMBED) return;
    int row = i >> 6, l = i & 63;
    out[i]                     = Ug[(size_t)bu[row] * EMBED + l];
    out[BATCH * EMBED + i]     = V[(size_t)bp[row] * EMBED + l];
    out[2 * BATCH * EMBED + i] = V[(size_t)bn[row] * EMBED + l];
}

// ---------------- launch ----------------

static inline void build_csr(const int* rows, const int* cols, const float* vals, int nnz,
                             int n_rows, int* rowptr, int* wofs, int* bsums,
                             int* colE, float* valE, hipStream_t stream) {
    const int nb = (n_rows + 1023) / 1024;
    hipMemsetAsync(wofs, 0, n_rows * sizeof(int), stream);
    k_hist<<<(nnz + 255) / 256, 256, 0, stream>>>(rows, wofs, nnz);
    k_scan1<<<nb, 1024, 0, stream>>>(wofs, rowptr, bsums, n_rows);
    k_scan2<<<1, 1024, 0, stream>>>(bsums, nb, &rowptr[n_rows]);
    k_scan3<<<(n_rows + 255) / 256, 256, 0, stream>>>(rowptr, wofs, bsums, n_rows);
    k_scatter<<<(nnz + 255) / 256, 256, 0, stream>>>(rows, cols, vals, wofs, colE, valE, nnz);
}

extern "C" void kernel_launch(void* const* d_in, const int* in_sizes, int n_in,
                              void* d_out, int out_size, void* d_ws, size_t ws_size,
                              hipStream_t stream) {
    const int*   batch_user = (const int*)d_in[0];
    const int*   batch_pos  = (const int*)d_in[1];
    const int*   batch_neg  = (const int*)d_in[2];
    const float* U     = (const float*)d_in[3];
    const float* V     = (const float*)d_in[4];
    const float* W0    = (const float*)d_in[5];
    const float* b0    = (const float*)d_in[6];
    const float* W1    = (const float*)d_in[7];
    const float* b1    = (const float*)d_in[8];
    const int*   S_row = (const int*)d_in[9];
    const int*   S_col = (const int*)d_in[10];
    const float* S_val = (const float*)d_in[11];
    const int*   R_row = (const int*)d_in[12];
    const int*   R_col = (const int*)d_in[13];
    const float* R_val = (const float*)d_in[14];
    float* out = (float*)d_out;

    const size_t tabElems = (size_t)NUM_USERS * EMBED;   // 6.4M floats

    // workspace layout (all 4-byte elems):
    float* A       = (float*)d_ws;                 // 6.4M   current user emb
    float* B       = A + tabElems;                 // 6.4M   aggregation
    int*   rowptrS = (int*)(B + tabElems);         // 100001
    int*   rowptrR = rowptrS + (NUM_USERS + 1);    // 100001
    int*   wofs    = rowptrR + (NUM_USERS + 1);    // 100000 cursor (reused)
    int*   bsums   = wofs + NUM_USERS;             // 128
    int*   edgebuf = bsums + 128;                  // max(2*S_NNZ, 2*R_NNZ) = 10M elems (shared S then R)

    const int spmm_blocks = (NUM_USERS * 64 + 255) / 256;   // one wave per row
    const int layer_blocks = (NUM_USERS + 3) / 4;

    // ---- CSR of S (reused for both layers) ----
    int*   ScolE = edgebuf;
    float* SvalE = (float*)(edgebuf + S_NNZ);
    build_csr(S_row, S_col, S_val, S_NNZ, NUM_USERS, rowptrS, wofs, bsums, ScolE, SvalE, stream);

    // layer 0: B = S @ U_in ; A = relu([B||U_in] @ W0 + b0)
    k_spmm_csr<<<spmm_blocks, 256, 0, stream>>>(rowptrS, ScolE, SvalE, U, B, NUM_USERS, 0);
    k_layer<<<layer_blocks, 256, 0, stream>>>(B, U, A, W0, b0);

    // layer 1: B = S @ A ; A = relu([B||A] @ W1 + b1)   (in-place on A, rows staged in LDS)
    k_spmm_csr<<<spmm_blocks, 256, 0, stream>>>(rowptrS, ScolE, SvalE, A, B, NUM_USERS, 0);
    k_layer<<<layer_blocks, 256, 0, stream>>>(B, A, A, W1, b1);

    // ---- CSR of R (reuses edge buffer) ----
    int*   RcolE = edgebuf;
    float* RvalE = (float*)(edgebuf + R_NNZ);
    build_csr(R_row, R_col, R_val, R_NNZ, NUM_USERS, rowptrR, wofs, bsums, RcolE, RvalE, stream);

    // user_g: A += R @ V
    k_spmm_csr<<<spmm_blocks, 256, 0, stream>>>(rowptrR, RcolE, RvalE, V, A, NUM_USERS, 1);

    // gathers
    k_gather<<<(BATCH * EMBED + 255) / 256, 256, 0, stream>>>(A, V, batch_user, batch_pos, batch_neg, out);
}

// Round 4
// 1564.559 us; speedup vs baseline: 1.7977x; 1.4042x over previous
//
#include <hip/hip_runtime.h>
#include <hip/hip_bf16.h>

#define NUM_USERS 100000
#define NUM_ITEMS 50000
#define EMBED     64
#define S_NNZ     (NUM_USERS * 32)
#define R_NNZ     (NUM_USERS * 50)
#define BATCH     8192

// ---------------- CSR build ----------------

__global__ void k_hist(const int* __restrict__ rows, int* __restrict__ cnt, int nnz) {
    int e = blockIdx.x * blockDim.x + threadIdx.x;
    if (e < nnz) atomicAdd(&cnt[rows[e]], 1);
}

__global__ __launch_bounds__(1024) void k_scan1(const int* __restrict__ cnt, int* __restrict__ excl,
                                                int* __restrict__ bsums, int n) {
    __shared__ int buf[1024];
    int t = threadIdx.x;
    int i = blockIdx.x * 1024 + t;
    int x = (i < n) ? cnt[i] : 0;
    buf[t] = x;
    __syncthreads();
    for (int off = 1; off < 1024; off <<= 1) {
        int y = (t >= off) ? buf[t - off] : 0;
        __syncthreads();
        buf[t] += y;
        __syncthreads();
    }
    if (i < n) excl[i] = buf[t] - x;
    if (t == 1023) bsums[blockIdx.x] = buf[1023];
}

__global__ __launch_bounds__(1024) void k_scan2(int* __restrict__ bsums, int nb, int* __restrict__ total_slot) {
    __shared__ int buf[1024];
    int t = threadIdx.x;
    int x = (t < nb) ? bsums[t] : 0;
    buf[t] = x;
    __syncthreads();
    for (int off = 1; off < 1024; off <<= 1) {
        int y = (t >= off) ? buf[t - off] : 0;
        __syncthreads();
        buf[t] += y;
        __syncthreads();
    }
    if (t < nb) bsums[t] = buf[t] - x;
    if (t == 1023) total_slot[0] = buf[1023];
}

__global__ void k_scan3(int* __restrict__ rowptr, int* __restrict__ wofs, const int* __restrict__ bsums, int n) {
    int i = blockIdx.x * blockDim.x + threadIdx.x;
    if (i < n) {
        int v = rowptr[i] + bsums[i >> 10];
        rowptr[i] = v;
        wofs[i]   = v;
    }
}

__global__ void k_scatter(const int* __restrict__ rows, const int* __restrict__ cols,
                          const float* __restrict__ vals, int* __restrict__ wofs,
                          int* __restrict__ colE, float* __restrict__ valE, int nnz) {
    int e = blockIdx.x * blockDim.x + threadIdx.x;
    if (e >= nnz) return;
    int r   = rows[e];
    int pos = atomicAdd(&wofs[r], 1);
    colE[pos] = cols[e];
    valE[pos] = vals[e];
}

// ---------------- SpMM (CSR, gather, unrolled x8 for MLP) ----------------
// One 64-lane wave per row; lane = embed dim; 8 independent gathers in flight.
__global__ __launch_bounds__(256) void k_spmm_csr(const int* __restrict__ rowptr,
                                                  const int* __restrict__ colE,
                                                  const float* __restrict__ valE,
                                                  const float* __restrict__ X,
                                                  float* __restrict__ Y,
                                                  int n_rows, int accumulate) {
    int w    = blockIdx.x * (blockDim.x >> 6) + (threadIdx.x >> 6);
    int lane = threadIdx.x & 63;
    if (w >= n_rows) return;
    int beg = rowptr[w], end = rowptr[w + 1];
    size_t oidx = (size_t)w * EMBED + lane;
    float acc = accumulate ? Y[oidx] : 0.0f;

    int j    = beg;
    int jend = beg + ((end - beg) & ~7);
    for (; j < jend; j += 8) {
        int   c[8];
        float v[8];
#pragma unroll
        for (int u = 0; u < 8; ++u) { c[u] = colE[j + u]; v[u] = valE[j + u]; }
        float x[8];
#pragma unroll
        for (int u = 0; u < 8; ++u) x[u] = X[(size_t)c[u] * EMBED + lane];
#pragma unroll
        for (int u = 0; u < 8; ++u) acc = fmaf(v[u], x[u], acc);
    }
    for (; j < end; ++j) acc = fmaf(valE[j], X[(size_t)colE[j] * EMBED + lane], acc);

    Y[oidx] = acc;
}

// ---------------- dense layer ----------------
// Uout <- relu(concat([Agg, Uin]) @ W + b). 16 rows per 256-thread block
// (W tile loaded once per block, amortized over 16 rows).
__global__ __launch_bounds__(256) void k_layer(const float* __restrict__ Agg,
                                               const float* __restrict__ Uin,
                                               float* __restrict__ Uout,
                                               const float* __restrict__ W,
                                               const float* __restrict__ b) {
    __shared__ float Wl[128 * 64];   // 32 KB
    __shared__ float xs[16][128];    // 8 KB
    int t = threadIdx.x;
    for (int i = t; i < 128 * 64; i += 256) Wl[i] = W[i];
    int rl = t >> 6;          // wave id 0..3
    int c  = t & 63;          // output column
    int rbase = blockIdx.x * 16;
    // stage 16 rows (4 per wave)
#pragma unroll
    for (int q = 0; q < 4; ++q) {
        int rr = rbase + rl * 4 + q;
        if (rr < NUM_USERS) {
            xs[rl * 4 + q][c]      = Agg[(size_t)rr * EMBED + c];
            xs[rl * 4 + q][64 + c] = Uin[(size_t)rr * EMBED + c];
        }
    }
    __syncthreads();
    float bias = b[c];
#pragma unroll
    for (int q = 0; q < 4; ++q) {
        int rr = rbase + rl * 4 + q;
        if (rr >= NUM_USERS) break;
        float acc = bias;
#pragma unroll
        for (int k = 0; k < 128; ++k) acc = fmaf(xs[rl * 4 + q][k], Wl[k * 64 + c], acc);
        Uout[(size_t)rr * EMBED + c] = fmaxf(acc, 0.0f);
    }
}

// ---------------- final gathers ----------------
__global__ void k_gather(const float* __restrict__ Ug, const float* __restrict__ V,
                         const int* __restrict__ bu, const int* __restrict__ bp,
                         const int* __restrict__ bn, float* __restrict__ out) {
    int i = blockIdx.x * blockDim.x + threadIdx.x;
    if (i >= BATCH * EMBED) return;
    int row = i >> 6, l = i & 63;
    out[i]                     = Ug[(size_t)bu[row] * EMBED + l];
    out[BATCH * EMBED + i]     = V[(size_t)bp[row] * EMBED + l];
    out[2 * BATCH * EMBED + i] = V[(size_t)bn[row] * EMBED + l];
}

// ---------------- launch ----------------

static inline void build_csr(const int* rows, const int* cols, const float* vals, int nnz,
                             int n_rows, int* rowptr, int* wofs, int* bsums,
                             int* colE, float* valE, hipStream_t stream) {
    const int nb = (n_rows + 1023) / 1024;
    hipMemsetAsync(wofs, 0, n_rows * sizeof(int), stream);
    k_hist<<<(nnz + 255) / 256, 256, 0, stream>>>(rows, wofs, nnz);
    k_scan1<<<nb, 1024, 0, stream>>>(wofs, rowptr, bsums, n_rows);
    k_scan2<<<1, 1024, 0, stream>>>(bsums, nb, &rowptr[n_rows]);
    k_scan3<<<(n_rows + 255) / 256, 256, 0, stream>>>(rowptr, wofs, bsums, n_rows);
    k_scatter<<<(nnz + 255) / 256, 256, 0, stream>>>(rows, cols, vals, wofs, colE, valE, nnz);
}

extern "C" void kernel_launch(void* const* d_in, const int* in_sizes, int n_in,
                              void* d_out, int out_size, void* d_ws, size_t ws_size,
                              hipStream_t stream) {
    const int*   batch_user = (const int*)d_in[0];
    const int*   batch_pos  = (const int*)d_in[1];
    const int*   batch_neg  = (const int*)d_in[2];
    const float* U     = (const float*)d_in[3];
    const float* V     = (const float*)d_in[4];
    const float* W0    = (const float*)d_in[5];
    const float* b0    = (const float*)d_in[6];
    const float* W1    = (const float*)d_in[7];
    const float* b1    = (const float*)d_in[8];
    const int*   S_row = (const int*)d_in[9];
    const int*   S_col = (const int*)d_in[10];
    const float* S_val = (const float*)d_in[11];
    const int*   R_row = (const int*)d_in[12];
    const int*   R_col = (const int*)d_in[13];
    const float* R_val = (const float*)d_in[14];
    float* out = (float*)d_out;

    const size_t tabElems = (size_t)NUM_USERS * EMBED;   // 6.4M floats

    float* A       = (float*)d_ws;                 // 6.4M   current user emb
    float* B       = A + tabElems;                 // 6.4M   aggregation
    int*   rowptrS = (int*)(B + tabElems);         // 100001
    int*   rowptrR = rowptrS + (NUM_USERS + 1);    // 100001
    int*   wofs    = rowptrR + (NUM_USERS + 1);    // 100000
    int*   bsums   = wofs + NUM_USERS;             // 128
    int*   edgebuf = bsums + 128;                  // 2*R_NNZ max = 10M elems

    const int spmm_blocks  = (NUM_USERS * 64 + 255) / 256;
    const int layer_blocks = (NUM_USERS + 15) / 16;

    // ---- CSR of S (reused for both layers) ----
    int*   ScolE = edgebuf;
    float* SvalE = (float*)(edgebuf + S_NNZ);
    build_csr(S_row, S_col, S_val, S_NNZ, NUM_USERS, rowptrS, wofs, bsums, ScolE, SvalE, stream);

    // layer 0
    k_spmm_csr<<<spmm_blocks, 256, 0, stream>>>(rowptrS, ScolE, SvalE, U, B, NUM_USERS, 0);
    k_layer<<<layer_blocks, 256, 0, stream>>>(B, U, A, W0, b0);

    // layer 1 (in-place on A; rows staged in LDS before write)
    k_spmm_csr<<<spmm_blocks, 256, 0, stream>>>(rowptrS, ScolE, SvalE, A, B, NUM_USERS, 0);
    k_layer<<<layer_blocks, 256, 0, stream>>>(B, A, A, W1, b1);

    // ---- CSR of R ----
    int*   RcolE = edgebuf;
    float* RvalE = (float*)(edgebuf + R_NNZ);
    build_csr(R_row, R_col, R_val, R_NNZ, NUM_USERS, rowptrR, wofs, bsums, RcolE, RvalE, stream);

    // user_g: A += R @ V
    k_spmm_csr<<<spmm_blocks, 256, 0, stream>>>(rowptrR, RcolE, RvalE, V, A, NUM_USERS, 1);

    // gathers
    k_gather<<<(BATCH * EMBED + 255) / 256, 256, 0, stream>>>(A, V, batch_user, batch_pos, batch_neg, out);
}

// Round 6
// 776.849 us; speedup vs baseline: 3.6205x; 2.0140x over previous
//
#include <hip/hip_runtime.h>
#include <hip/hip_bf16.h>

#define NUM_USERS 100000
#define NUM_ITEMS 50000
#define EMBED     64
#define S_NNZ     (NUM_USERS * 32)
#define R_NNZ     (NUM_USERS * 50)
#define BATCH     8192

// ---------------- CSR build (S only) ----------------

__global__ void k_hist(const int* __restrict__ rows, int* __restrict__ cnt, int nnz) {
    int e = blockIdx.x * blockDim.x + threadIdx.x;
    if (e < nnz) atomicAdd(&cnt[rows[e]], 1);
}

__global__ __launch_bounds__(1024) void k_scan1(const int* __restrict__ cnt, int* __restrict__ excl,
                                                int* __restrict__ bsums, int n) {
    __shared__ int buf[1024];
    int t = threadIdx.x;
    int i = blockIdx.x * 1024 + t;
    int x = (i < n) ? cnt[i] : 0;
    buf[t] = x;
    __syncthreads();
    for (int off = 1; off < 1024; off <<= 1) {
        int y = (t >= off) ? buf[t - off] : 0;
        __syncthreads();
        buf[t] += y;
        __syncthreads();
    }
    if (i < n) excl[i] = buf[t] - x;
    if (t == 1023) bsums[blockIdx.x] = buf[1023];
}

__global__ __launch_bounds__(1024) void k_scan2(int* __restrict__ bsums, int nb, int* __restrict__ total_slot) {
    __shared__ int buf[1024];
    int t = threadIdx.x;
    int x = (t < nb) ? bsums[t] : 0;
    buf[t] = x;
    __syncthreads();
    for (int off = 1; off < 1024; off <<= 1) {
        int y = (t >= off) ? buf[t - off] : 0;
        __syncthreads();
        buf[t] += y;
        __syncthreads();
    }
    if (t < nb) bsums[t] = buf[t] - x;
    if (t == 1023) total_slot[0] = buf[1023];
}

__global__ void k_scan3(int* __restrict__ rowptr, int* __restrict__ wofs, const int* __restrict__ bsums, int n) {
    int i = blockIdx.x * blockDim.x + threadIdx.x;
    if (i < n) {
        int v = rowptr[i] + bsums[i >> 10];
        rowptr[i] = v;
        wofs[i]   = v;
    }
}

// counting-sort scatter, packed (col,val) 8B single write per edge
__global__ void k_scatter(const int* __restrict__ rows, const int* __restrict__ cols,
                          const float* __restrict__ vals, int* __restrict__ wofs,
                          int2* __restrict__ colval, int nnz) {
    int e = blockIdx.x * blockDim.x + threadIdx.x;
    if (e >= nnz) return;
    int r   = rows[e];
    int pos = atomicAdd(&wofs[r], 1);
    colval[pos] = make_int2(cols[e], __float_as_int(vals[e]));
}

// ---------------- SpMM (CSR gather, packed edges, unroll x8) ----------------
__global__ __launch_bounds__(256) void k_spmm_csr(const int* __restrict__ rowptr,
                                                  const int2* __restrict__ colval,
                                                  const float* __restrict__ X,
                                                  float* __restrict__ Y, int n_rows) {
    int w    = blockIdx.x * (blockDim.x >> 6) + (threadIdx.x >> 6);
    int lane = threadIdx.x & 63;
    if (w >= n_rows) return;
    int beg = rowptr[w], end = rowptr[w + 1];
    float acc = 0.0f;
    int j    = beg;
    int jend = beg + ((end - beg) & ~7);
    for (; j < jend; j += 8) {
        int2 cv[8];
#pragma unroll
        for (int u = 0; u < 8; ++u) cv[u] = colval[j + u];
        float x[8];
#pragma unroll
        for (int u = 0; u < 8; ++u) x[u] = X[(size_t)cv[u].x * EMBED + lane];
#pragma unroll
        for (int u = 0; u < 8; ++u) acc = fmaf(__int_as_float(cv[u].y), x[u], acc);
    }
    for (; j < end; ++j) acc = fmaf(__int_as_float(colval[j].y), X[(size_t)colval[j].x * EMBED + lane], acc);
    Y[(size_t)w * EMBED + lane] = acc;
}

// Batch-restricted SpMM: wave i computes (S @ X)[bu[i]] -> Agg2[i]
__global__ __launch_bounds__(256) void k_spmm_batch(const int* __restrict__ rowptr,
                                                    const int2* __restrict__ colval,
                                                    const float* __restrict__ X,
                                                    const int* __restrict__ bu,
                                                    float* __restrict__ Agg2, int n) {
    int w    = blockIdx.x * (blockDim.x >> 6) + (threadIdx.x >> 6);
    int lane = threadIdx.x & 63;
    if (w >= n) return;
    int r   = bu[w];
    int beg = rowptr[r], end = rowptr[r + 1];
    float acc = 0.0f;
    int j    = beg;
    int jend = beg + ((end - beg) & ~7);
    for (; j < jend; j += 8) {
        int2 cv[8];
#pragma unroll
        for (int u = 0; u < 8; ++u) cv[u] = colval[j + u];
        float x[8];
#pragma unroll
        for (int u = 0; u < 8; ++u) x[u] = X[(size_t)cv[u].x * EMBED + lane];
#pragma unroll
        for (int u = 0; u < 8; ++u) acc = fmaf(__int_as_float(cv[u].y), x[u], acc);
    }
    for (; j < end; ++j) acc = fmaf(__int_as_float(colval[j].y), X[(size_t)colval[j].x * EMBED + lane], acc);
    Agg2[(size_t)w * EMBED + lane] = acc;
}

// ---------------- dense layers ----------------
__global__ __launch_bounds__(256) void k_layer(const float* __restrict__ Agg,
                                               const float* __restrict__ Uin,
                                               float* __restrict__ Uout,
                                               const float* __restrict__ W,
                                               const float* __restrict__ b) {
    __shared__ float Wl[128 * 64];
    __shared__ float xs[16][128];
    int t = threadIdx.x;
    for (int i = t; i < 128 * 64; i += 256) Wl[i] = W[i];
    int rl = t >> 6;
    int c  = t & 63;
    int rbase = blockIdx.x * 16;
#pragma unroll
    for (int q = 0; q < 4; ++q) {
        int rr = rbase + rl * 4 + q;
        if (rr < NUM_USERS) {
            xs[rl * 4 + q][c]      = Agg[(size_t)rr * EMBED + c];
            xs[rl * 4 + q][64 + c] = Uin[(size_t)rr * EMBED + c];
        }
    }
    __syncthreads();
    float bias = b[c];
#pragma unroll
    for (int q = 0; q < 4; ++q) {
        int rr = rbase + rl * 4 + q;
        if (rr >= NUM_USERS) break;
        float acc = bias;
#pragma unroll
        for (int k = 0; k < 128; ++k) acc = fmaf(xs[rl * 4 + q][k], Wl[k * 64 + c], acc);
        Uout[(size_t)rr * EMBED + c] = fmaxf(acc, 0.0f);
    }
}

__global__ __launch_bounds__(256) void k_layer_batch(const float* __restrict__ Agg2,
                                                     const float* __restrict__ Uin,
                                                     const int* __restrict__ bu,
                                                     float* __restrict__ out0,
                                                     const float* __restrict__ W,
                                                     const float* __restrict__ b) {
    __shared__ float Wl[128 * 64];
    __shared__ float xs[16][128];
    int t = threadIdx.x;
    for (int i = t; i < 128 * 64; i += 256) Wl[i] = W[i];
    int rl = t >> 6;
    int c  = t & 63;
    int rbase = blockIdx.x * 16;
#pragma unroll
    for (int q = 0; q < 4; ++q) {
        int s = rbase + rl * 4 + q;
        if (s < BATCH) {
            xs[rl * 4 + q][c]      = Agg2[(size_t)s * EMBED + c];
            xs[rl * 4 + q][64 + c] = Uin[(size_t)bu[s] * EMBED + c];
        }
    }
    __syncthreads();
    float bias = b[c];
#pragma unroll
    for (int q = 0; q < 4; ++q) {
        int s = rbase + rl * 4 + q;
        if (s >= BATCH) break;
        float acc = bias;
#pragma unroll
        for (int k = 0; k < 128; ++k) acc = fmaf(xs[rl * 4 + q][k], Wl[k * 64 + c], acc);
        out0[(size_t)s * EMBED + c] = fmaxf(acc, 0.0f);
    }
}

// ---------------- R handling (no CSR): chain map + edge filter ----------------

__global__ void k_chain(const int* __restrict__ bu, int* __restrict__ head,
                        int* __restrict__ nxt, int n) {
    int i = blockIdx.x * blockDim.x + threadIdx.x;
    if (i < n) nxt[i] = atomicExch(&head[bu[i]], i);
}

__global__ __launch_bounds__(256) void k_filter(const int* __restrict__ rows,
                                                const int* __restrict__ cols,
                                                const float* __restrict__ vals,
                                                const int* __restrict__ head,
                                                const int* __restrict__ nxt,
                                                const float* __restrict__ V,
                                                float* __restrict__ out0, int nnz) {
    int e    = blockIdx.x * blockDim.x + threadIdx.x;
    int lane = threadIdx.x & 63;
    int r = (e < nnz) ? rows[e] : -1;
    int h = (r >= 0) ? head[r] : -1;
    unsigned long long mask = __ballot(h >= 0);
    int   c = 0;
    float v = 0.0f;
    if (h >= 0) { c = cols[e]; v = vals[e]; }
    while (mask) {
        int l = __ffsll((long long)mask) - 1;
        mask &= mask - 1;
        int   cc = __shfl(c, l);
        float vv = __shfl(v, l);
        int   hh = __shfl(h, l);
        float x  = vv * V[(size_t)cc * EMBED + lane];
        while (hh >= 0) {
            atomicAdd(&out0[(size_t)hh * EMBED + lane], x);
            hh = nxt[hh];
        }
    }
}

// ---------------- final gathers (bp/bn only) ----------------
__global__ void k_gather2(const float* __restrict__ V,
                          const int* __restrict__ bp, const int* __restrict__ bn,
                          float* __restrict__ out) {
    int i = blockIdx.x * blockDim.x + threadIdx.x;
    if (i >= BATCH * EMBED) return;
    int row = i >> 6, l = i & 63;
    out[BATCH * EMBED + i]     = V[(size_t)bp[row] * EMBED + l];
    out[2 * BATCH * EMBED + i] = V[(size_t)bn[row] * EMBED + l];
}

// ---------------- launch ----------------

extern "C" void kernel_launch(void* const* d_in, const int* in_sizes, int n_in,
                              void* d_out, int out_size, void* d_ws, size_t ws_size,
                              hipStream_t stream) {
    const int*   batch_user = (const int*)d_in[0];
    const int*   batch_pos  = (const int*)d_in[1];
    const int*   batch_neg  = (const int*)d_in[2];
    const float* U     = (const float*)d_in[3];
    const float* V     = (const float*)d_in[4];
    const float* W0    = (const float*)d_in[5];
    const float* b0    = (const float*)d_in[6];
    const float* W1    = (const float*)d_in[7];
    const float* b1    = (const float*)d_in[8];
    const int*   S_row = (const int*)d_in[9];
    const int*   S_col = (const int*)d_in[10];
    const float* S_val = (const float*)d_in[11];
    const int*   R_row = (const int*)d_in[12];
    const int*   R_col = (const int*)d_in[13];
    const float* R_val = (const float*)d_in[14];
    float* out = (float*)d_out;

    const size_t tabElems = (size_t)NUM_USERS * EMBED;   // 6.4M floats

    // workspace layout (byte offsets, 8B-aligned chunks)
    char* wsb = (char*)d_ws;
    size_t o = 0;
    float* A       = (float*)(wsb + o); o += tabElems * 4;            // U1
    float* B       = (float*)(wsb + o); o += tabElems * 4;            // agg
    float* Agg2    = (float*)(wsb + o); o += (size_t)BATCH * EMBED * 4;
    int*   rowptrS = (int*)(wsb + o);   o += (NUM_USERS + 1) * 4;
    int*   wofs    = (int*)(wsb + o);   o += NUM_USERS * 4;
    int*   bsums   = (int*)(wsb + o);   o += 1024 * 4;
    int*   head    = (int*)(wsb + o);   o += NUM_USERS * 4;
    int*   nxt     = (int*)(wsb + o);   o += BATCH * 4;
    o = (o + 7) & ~(size_t)7;
    int2*  colvalS = (int2*)(wsb + o);  o += (size_t)S_NNZ * 8;

    const int nb = (NUM_USERS + 1023) / 1024;
    const int spmm_blocks  = (NUM_USERS * 64 + 255) / 256;
    const int layer_blocks = (NUM_USERS + 15) / 16;

    // ---- CSR of S ----
    hipMemsetAsync(wofs, 0, NUM_USERS * sizeof(int), stream);
    k_hist<<<(S_NNZ + 255) / 256, 256, 0, stream>>>(S_row, wofs, S_NNZ);
    k_scan1<<<nb, 1024, 0, stream>>>(wofs, rowptrS, bsums, NUM_USERS);
    k_scan2<<<1, 1024, 0, stream>>>(bsums, nb, &rowptrS[NUM_USERS]);
    k_scan3<<<(NUM_USERS + 255) / 256, 256, 0, stream>>>(rowptrS, wofs, bsums, NUM_USERS);
    k_scatter<<<(S_NNZ + 255) / 256, 256, 0, stream>>>(S_row, S_col, S_val, wofs, colvalS, S_NNZ);

    // ---- layer 0 (full) ----
    k_spmm_csr<<<spmm_blocks, 256, 0, stream>>>(rowptrS, colvalS, U, B, NUM_USERS);
    k_layer<<<layer_blocks, 256, 0, stream>>>(B, U, A, W0, b0);

    // ---- chain map for R (user -> batch slots) ----
    hipMemsetAsync(head, 0xFF, NUM_USERS * sizeof(int), stream);
    k_chain<<<(BATCH + 255) / 256, 256, 0, stream>>>(batch_user, head, nxt, BATCH);

    // ---- layer 1 (batch-restricted), writes u2 into out0 ----
    k_spmm_batch<<<(BATCH * 64 + 255) / 256, 256, 0, stream>>>(rowptrS, colvalS, A, batch_user, Agg2, BATCH);
    k_layer_batch<<<(BATCH + 15) / 16, 256, 0, stream>>>(Agg2, A, batch_user, out, W1, b1);

    // ---- out0 += (R @ V)[batch rows] ----
    k_filter<<<(R_NNZ + 255) / 256, 256, 0, stream>>>(R_row, R_col, R_val, head, nxt, V, out, R_NNZ);

    // ---- bp/bn gathers ----
    k_gather2<<<(BATCH * EMBED + 255) / 256, 256, 0, stream>>>(V, batch_pos, batch_neg, out);
}